// Round 3
// baseline (471.869 us; speedup 1.0000x reference)
//
#include <hip/hip_runtime.h>

// Problem constants
#define Bsz 16
#define Dch 1024
#define Tsz 1024
#define Hsz 1024
#define Mtot (Bsz*Tsz)   // 16384
#define K2   (2*Dch)     // 2048
#define Ntot (3*Hsz)     // 3072
#define NCH  16          // scan chunks per chain
#define CL   64          // chunk length (NCH*CL == Tsz)
#define NT   32          // K-tiles in GEMM (K2/64)

typedef __attribute__((ext_vector_type(8))) short bf16x8;
typedef __attribute__((ext_vector_type(4))) float f32x4;

__device__ __forceinline__ unsigned short f2bf(float x) {
    unsigned u = __float_as_uint(x);
    u += 0x7FFFu + ((u >> 16) & 1u);   // round-to-nearest-even
    return (unsigned short)(u >> 16);
}
__device__ __forceinline__ float bf2f(unsigned short s) {
    return __uint_as_float(((unsigned)s) << 16);
}

// async global->LDS, 16B per lane, dest = ldsbase + lane*16 (wave-uniform base)
#define GLOAD_LDS16(gp, lp) \
    __builtin_amdgcn_global_load_lds((const __attribute__((address_space(1))) void*)(gp), \
                                     (__attribute__((address_space(3))) void*)(lp), 16, 0, 0)

// generic LDS pointer -> 32-bit LDS byte offset (for inline-asm ds_read)
#define LDSB(p) ((unsigned)(unsigned long long)(__attribute__((address_space(3))) const void*)(p))

// inline-asm ds_read_b128 (invisible to SIInsertWaitcnts; arrival enforced by
// our counted lgkmcnt + sched_barrier per rule #18)
#define DSR(dst, addr, off) \
    asm volatile("ds_read_b128 %0, %1 offset:" #off : "=v"(dst) : "v"(addr))

// counted lgkmcnt wait + scheduling fence
#define WAITLG(n) do { \
    asm volatile("s_waitcnt lgkmcnt(" #n ")" ::: "memory"); \
    __builtin_amdgcn_sched_barrier(0); } while (0)

// Merged prep: blocks [0,4096) build A2 (LDS transpose + causal shift + bf16 pack);
// blocks [4096,5632) cast conv_w fp32->bf16 (flat layout IS B^T row-major already).
__global__ __launch_bounds__(256)
void prep(const float* __restrict__ x, unsigned short* __restrict__ a2,
          const float* __restrict__ w, unsigned short* __restrict__ wb) {
    __shared__ float Xs[64][66];
    int bid = blockIdx.x;
    int tid = threadIdx.x;
    if (bid >= 4096) {
        int i0 = (bid - 4096) * 256 + tid;
        #pragma unroll
        for (int k = 0; k < 4; k++) {
            int i = i0 + k * (1536 * 256);
            float4 v = ((const float4*)w)[i];
            ushort4 r;
            r.x = f2bf(v.x); r.y = f2bf(v.y); r.z = f2bf(v.z); r.w = f2bf(v.w);
            ((ushort4*)wb)[i] = r;
        }
        return;
    }
    int b   = bid >> 8;
    int tt0 = ((bid >> 4) & 15) << 6;
    int dd0 = (bid & 15) << 6;
    int colt = tid & 63, rowq = tid >> 6;
    const size_t xbase = (size_t)b * (Dch * Tsz);
    #pragma unroll
    for (int r = 0; r < 16; r++) {
        int dd = r * 4 + rowq;
        Xs[dd][1 + colt] = x[xbase + (size_t)(dd0 + dd) * Tsz + tt0 + colt];
    }
    if (tid < 64) {
        Xs[tid][0] = (tt0 == 0) ? 0.f : x[xbase + (size_t)(dd0 + tid) * Tsz + tt0 - 1];
    }
    __syncthreads();
    #pragma unroll
    for (int r = 0; r < 16; r++) {
        int tr = r * 4 + rowq;
        int dc = colt;
        float v0 = Xs[dc][tr];       // x[t-1]
        float v1 = Xs[dc][tr + 1];   // x[t]
        unsigned pack = (unsigned)f2bf(v0) | ((unsigned)f2bf(v1) << 16);
        int m = (b << 10) + tt0 + tr;
        ((unsigned*)a2)[(size_t)m * (K2 / 2) + dd0 + dc] = pack;
    }
}

// ===========================================================================
// 256x256-tile, BK=64, 8-wave (2Mx4N), ds_read-PIPELINED 4-phase schedule.
//
// R3 change: reads are issued ONE PHASE AHEAD with counted lgkmcnt, so the
// LDS pipe drains DURING the MFMA clusters (previously barriers globally
// separated read-windows from MFMA-windows -> LDS+MFMA fully serialized:
// 5875 cyc/tile measured vs ~2800 overlapped floor).
//
// MFMA clusters by quadrant (i-quad a, j-half b), 16 MFMA each; read sets
// are register-DISJOINT from the concurrently-running cluster:
//   C(0,0) <- R0 = {A0-3, B0-1} (12 rds)   C(0,1) <- R1 = {B2-3} (4 rds)
//   C(1,0) <- R2 = {A4-7} (8 rds)          C(1,1) <- R3 = {} (0 rds)
// Phase p: issue R(p+1); stage; lgkmcnt(#issued) proves R(p); MFMA C(p); barrier.
// ph2 ends with vmcnt(2)+barrier = PUBLISH(t+1): proves A1(t+1) (staged t.ph0)
// and all older halves landed; ph3 then reads R0(t+1) from buf[nxt] safely.
// Stage schedule: ph0: A1(t+1)->buf[nxt]; ph2: B1(t+2)->buf[cur];
//                 ph3: B0(t+2), A0(t+2)->buf[cur].
// WAR proof chain: region staged in phase p was read by R-sets whose
// completion each reader proved via lgkmcnt BEFORE a barrier < stage issue:
//   B-half1: R0 proven<close(ph0), R1 proven<close(ph1) -> stage ph2 OK
//   B-half0: same -> stage ph3 OK;  A-half0: R2 proven<close(ph2) -> ph3 OK
//   A1(t+1)->other buffer, readers were tile t-1 -> OK.
// One barrier per phase suffices (it carries the cross-wave lgkmcnt proof).
// DS returns are in-order (uniform ds_read lgkm queue) -> counted waits exact.
// ===========================================================================
#define MFMA_QUAD(a0, b0) do { \
    _Pragma("unroll") for (int ks_ = 0; ks_ < 2; ++ks_) { \
      _Pragma("unroll") for (int di_ = 0; di_ < 4; ++di_) { \
        _Pragma("unroll") for (int dj_ = 0; dj_ < 2; ++dj_) { \
          acc[(a0)*4+di_][(b0)*2+dj_] = __builtin_amdgcn_mfma_f32_16x16x32_bf16( \
              af[(a0)*4+di_][ks_], bfr[ks_][(b0)*2+dj_], acc[(a0)*4+di_][(b0)*2+dj_], 0, 0, 0); \
        } } } } while (0)

__global__ __launch_bounds__(512, 2)
void gemm_gates(const unsigned short* __restrict__ A, const unsigned short* __restrict__ Bt,
                const float* __restrict__ bias,
                float* __restrict__ zc, float* __restrict__ fh, unsigned short* __restrict__ ob) {
    __shared__ __align__(16) unsigned short As[2][16384];
    __shared__ __align__(16) unsigned short Bs[2][16384];

    int tid  = threadIdx.x;
    int wv   = tid >> 6, lane = tid & 63;
    int wm   = wv >> 2, wn = wv & 3;        // 2 x 4 waves -> 128x64 per wave
    int lm   = lane & 15, q = lane >> 4;

    // XCD-aware bijective swizzle: 768 wgs = 8 XCDs x 96
    int bid = blockIdx.x;
    int swz = (bid & 7) * 96 + (bid >> 3);
    int mt = swz / 12, nt = swz % 12;       // 64 m-tiles x 12 n-tiles
    int m0 = mt << 8, n0 = nt << 8;

    const unsigned short* Abase = A  + (size_t)m0 * K2;
    const unsigned short* Bbase = Bt + (size_t)n0 * K2;

    // staging: lane covers row (wv*8 + l>>3), chunk (l&7); global chunk
    // pre-swizzled by ^(row&7) = ^(l>>3); LDS dest linear.
    int loff   = (wv * 8 + (lane >> 3)) * K2 + (((lane & 7) ^ (lane >> 3)) << 3);
    int ldsoff = wv * 8 * 64;

    // fragment-read constants (ushort units)
    int sw  = lm & 7;
    int kc0 = (q ^ sw) << 3;          // k-slice 0 -> chunks 0..3
    int kc1 = ((4 + q) ^ sw) << 3;    // k-slice 1 -> chunks 4..7
    int aoff = (wm * 128 + lm) * 64;
    int boff = (wn * 64 + lm) * 64;

    unsigned asb = LDSB(&As[0][0]);
    unsigned bsb = LDSB(&Bs[0][0]);
    unsigned aA0 = asb + (unsigned)(aoff + kc0) * 2u;
    unsigned aA1 = asb + (unsigned)(aoff + kc1) * 2u;
    unsigned aB0 = bsb + (unsigned)(boff + kc0) * 2u;
    unsigned aB1 = bsb + (unsigned)(boff + kc1) * 2u;

    f32x4 acc[8][4] = {};
    bf16x8 af[8][2], bfr[2][4];

#define STAGE_A(t, h) do { \
    const unsigned short* g_ = Abase + (h) * (128 * K2) + (t) * 64 + loff; \
    unsigned short* l_ = &As[(t) & 1][(h) * 8192 + ldsoff]; \
    GLOAD_LDS16(g_, l_); \
    GLOAD_LDS16(g_ + 64 * K2, l_ + 64 * 64); } while (0)
#define STAGE_B(t, h) do { \
    const unsigned short* g_ = Bbase + (h) * (128 * K2) + (t) * 64 + loff; \
    unsigned short* l_ = &Bs[(t) & 1][(h) * 8192 + ldsoff]; \
    GLOAD_LDS16(g_, l_); \
    GLOAD_LDS16(g_ + 64 * K2, l_ + 64 * 64); } while (0)

// read groups (bo = buffer byte offset 0 / 32768)
#define R_B01(bo) do { \
    DSR(bfr[0][0], aB0 + (bo), 0);    DSR(bfr[1][0], aB1 + (bo), 0); \
    DSR(bfr[0][1], aB0 + (bo), 2048); DSR(bfr[1][1], aB1 + (bo), 2048); } while (0)
#define R_B23(bo) do { \
    DSR(bfr[0][2], aB0 + (bo), 4096); DSR(bfr[1][2], aB1 + (bo), 4096); \
    DSR(bfr[0][3], aB0 + (bo), 6144); DSR(bfr[1][3], aB1 + (bo), 6144); } while (0)
#define R_A03(bo) do { \
    DSR(af[0][0], aA0 + (bo), 0);    DSR(af[0][1], aA1 + (bo), 0); \
    DSR(af[1][0], aA0 + (bo), 2048); DSR(af[1][1], aA1 + (bo), 2048); \
    DSR(af[2][0], aA0 + (bo), 4096); DSR(af[2][1], aA1 + (bo), 4096); \
    DSR(af[3][0], aA0 + (bo), 6144); DSR(af[3][1], aA1 + (bo), 6144); } while (0)
#define R_A47(bo) do { \
    DSR(af[4][0], aA0 + (bo), 8192);  DSR(af[4][1], aA1 + (bo), 8192); \
    DSR(af[5][0], aA0 + (bo), 10240); DSR(af[5][1], aA1 + (bo), 10240); \
    DSR(af[6][0], aA0 + (bo), 12288); DSR(af[6][1], aA1 + (bo), 12288); \
    DSR(af[7][0], aA0 + (bo), 14336); DSR(af[7][1], aA1 + (bo), 14336); } while (0)

    // Prologue: tile0 (4 halves) + tile1's {B1,B0,A0}; A1(1) staged in 0.ph0.
    STAGE_A(0, 0); STAGE_A(0, 1); STAGE_B(0, 0); STAGE_B(0, 1);
    STAGE_B(1, 1); STAGE_B(1, 0); STAGE_A(1, 0);
    asm volatile("s_waitcnt vmcnt(6)" ::: "memory");   // tile0's 8 loads retired
    __builtin_amdgcn_s_barrier();
    R_B01(0u); R_A03(0u);                              // R0(0)
    __builtin_amdgcn_sched_barrier(0);

    #pragma unroll 2
    for (int t = 0; t < NT - 1; ++t) {
        unsigned cb = (t & 1) ? 32768u : 0u;
        unsigned nb = cb ^ 32768u;

        // ---- ph0: issue R1; stage A1(t+1)->buf[nxt]; wait R0; C(0,0)
        R_B23(cb);
        STAGE_A(t + 1, 1);
        WAITLG(4);
        __builtin_amdgcn_s_setprio(1);
        MFMA_QUAD(0, 0);
        __builtin_amdgcn_s_setprio(0);
        __builtin_amdgcn_sched_barrier(0);
        __builtin_amdgcn_s_barrier();

        // ---- ph1: issue R2; wait R1; C(0,1)
        R_A47(cb);
        WAITLG(8);
        __builtin_amdgcn_s_setprio(1);
        MFMA_QUAD(0, 1);
        __builtin_amdgcn_s_setprio(0);
        __builtin_amdgcn_sched_barrier(0);
        __builtin_amdgcn_s_barrier();

        // ---- ph2: stage B1(t+2); wait R2; C(1,0); PUBLISH(t+1)
        if (t + 2 < NT) STAGE_B(t + 2, 1);
        WAITLG(0);
        __builtin_amdgcn_s_setprio(1);
        MFMA_QUAD(1, 0);
        __builtin_amdgcn_s_setprio(0);
        __builtin_amdgcn_sched_barrier(0);
        if (t + 2 < NT) asm volatile("s_waitcnt vmcnt(2)" ::: "memory");
        else            asm volatile("s_waitcnt vmcnt(0)" ::: "memory");
        __builtin_amdgcn_s_barrier();   // publishes: tile t+1 fully in LDS

        // ---- ph3: issue R0(t+1) from buf[nxt]; stage B0/A0(t+2); C(1,1)
        R_B01(nb); R_A03(nb);
        if (t + 2 < NT) { STAGE_B(t + 2, 0); STAGE_A(t + 2, 0); }
        WAITLG(12);
        __builtin_amdgcn_s_setprio(1);
        MFMA_QUAD(1, 1);
        __builtin_amdgcn_s_setprio(0);
        __builtin_amdgcn_sched_barrier(0);
        __builtin_amdgcn_s_barrier();
    }

    // ---- peeled last tile (t = NT-1, buffer parity (NT-1)&1 = 1)
    {
        const unsigned cb = ((NT - 1) & 1) ? 32768u : 0u;
        R_B23(cb);
        WAITLG(4);
        __builtin_amdgcn_s_setprio(1);
        MFMA_QUAD(0, 0);
        __builtin_amdgcn_s_setprio(0);
        __builtin_amdgcn_sched_barrier(0);
        __builtin_amdgcn_s_barrier();
        R_A47(cb);
        WAITLG(8);
        __builtin_amdgcn_s_setprio(1);
        MFMA_QUAD(0, 1);
        __builtin_amdgcn_s_setprio(0);
        __builtin_amdgcn_sched_barrier(0);
        __builtin_amdgcn_s_barrier();
        WAITLG(0);
        __builtin_amdgcn_s_setprio(1);
        MFMA_QUAD(1, 0);
        MFMA_QUAD(1, 1);
        __builtin_amdgcn_s_setprio(0);
        __builtin_amdgcn_sched_barrier(0);
    }

    // Epilogue: C/D layout col=lane&15, row=(lane>>4)*4+reg.
    int gt = nt >> 2;   // 0:z(tanh) 1:f(sigm) 2:o(sigm->bf16)
    #pragma unroll
    for (int i = 0; i < 8; ++i) {
        int mrow = m0 + wm * 128 + i * 16 + q * 4;
        #pragma unroll
        for (int j = 0; j < 4; ++j) {
            int n = n0 + wn * 64 + j * 16 + lm;
            float bv = bias[n];
            int hcol = n & 1023;
            #pragma unroll
            for (int r = 0; r < 4; ++r) {
                float g = acc[i][j][r] + bv;
                size_t idx = (size_t)(mrow + r) * Hsz + hcol;
                if (gt == 0) {
                    float e = __expf(2.f * g);
                    zc[idx] = __fdividef(e - 1.f, e + 1.f);
                } else {
                    float s = __fdividef(1.f, 1.f + __expf(-g));
                    if (gt == 1) fh[idx] = s;
                    else         ob[idx] = f2bf(s);
                }
            }
        }
    }
}

// ---- chunked fo-pooling scan: c_t = z + f*(c - z), c_0 = 0 ----
__global__ __launch_bounds__(256)
void scan1(const float* __restrict__ zc, const float* __restrict__ fh,
           float* __restrict__ Aw, float* __restrict__ Bw) {
    int blk = blockIdx.x;                 // 16 b * 16 ch * 2 hb = 512
    int hb = blk & 1, ch = (blk >> 1) & 15, b = blk >> 5;
    int h = hb * 512 + threadIdx.x * 2;
    size_t base = ((size_t)b << 20) + ((size_t)(ch * CL) << 10) + h;
    float ax = 1.f, ay = 1.f, bx = 0.f, by = 0.f;
    #pragma unroll 8
    for (int s = 0; s < CL; s++) {
        size_t idx = base + ((size_t)s << 10);
        float2 z = *(const float2*)&zc[idx];
        float2 f = *(const float2*)&fh[idx];
        ax *= f.x; ay *= f.y;
        bx = z.x + f.x * (bx - z.x);
        by = z.y + f.y * (by - z.y);
    }
    int o = (ch * Bsz + b) * Hsz + h;
    *(float2*)&Aw[o] = make_float2(ax, ay);
    *(float2*)&Bw[o] = make_float2(bx, by);
}

__global__ __launch_bounds__(256)
void scan3(float* __restrict__ zc, float* __restrict__ fh,
           const unsigned short* __restrict__ ob,
           const float* __restrict__ Aw, const float* __restrict__ Bw) {
    int blk = blockIdx.x;                 // 512
    int hb = blk & 1, ch = (blk >> 1) & 15, b = blk >> 5;
    int h = hb * 512 + threadIdx.x * 2;
    float cx = 0.f, cy = 0.f;
    for (int cp = 0; cp < ch; cp++) {     // chunk-entry state (block-uniform trip)
        int o = (cp * Bsz + b) * Hsz + h;
        float2 A = *(const float2*)&Aw[o];
        float2 B = *(const float2*)&Bw[o];
        cx = A.x * cx + B.x;
        cy = A.y * cy + B.y;
    }
    size_t base = ((size_t)b << 20) + ((size_t)(ch * CL) << 10) + h;
    #pragma unroll 8
    for (int s = 0; s < CL; s++) {
        size_t idx = base + ((size_t)s << 10);
        float2 z = *(const float2*)&zc[idx];
        float2 f = *(const float2*)&fh[idx];
        unsigned ov = *(const unsigned*)&ob[idx];   // two bf16 o-gates
        cx = z.x + f.x * (cx - z.x);
        cy = z.y + f.y * (cy - z.y);
        *(float2*)&zc[idx] = make_float2(cx, cy);
        float ox = bf2f((unsigned short)(ov & 0xFFFF));
        float oy = bf2f((unsigned short)(ov >> 16));
        *(float2*)&fh[idx] = make_float2(ox * cx, oy * cy);
    }
}

extern "C" void kernel_launch(void* const* d_in, const int* in_sizes, int n_in,
                              void* d_out, int out_size, void* d_ws, size_t ws_size,
                              hipStream_t stream) {
    const float* x    = (const float*)d_in[0];   // [16,1024,1024]
    const float* w    = (const float*)d_in[1];   // [3072,1024,2]
    const float* bias = (const float*)d_in[2];   // [3072]
    float* zc = (float*)d_out;                               // c_seq out (holds z pre-scan)
    float* fh = (float*)d_out + (size_t)Mtot * Hsz;          // h_seq out (holds f pre-scan)
    unsigned short* a2 = (unsigned short*)d_ws;              // 64 MB
    unsigned short* wb = a2 + (size_t)Mtot * K2;             // 12.6 MB
    unsigned short* ob = wb + (size_t)Ntot * K2;             // 32 MB (o gate, bf16)
    float* Aw = (float*)(ob + (size_t)Mtot * Hsz);           // 1 MB
    float* Bw = Aw + NCH * Bsz * Hsz;                        // 1 MB

    hipLaunchKernelGGL(prep, dim3(5632), dim3(256), 0, stream, x, a2, w, wb);
    hipLaunchKernelGGL(gemm_gates, dim3(768), dim3(512), 0, stream, a2, wb, bias, zc, fh, ob);
    hipLaunchKernelGGL(scan1, dim3(512), dim3(256), 0, stream, zc, fh, Aw, Bw);
    hipLaunchKernelGGL(scan3, dim3(512), dim3(256), 0, stream, zc, fh, ob, Aw, Bw);
}

// Round 4
// 453.804 us; speedup vs baseline: 1.0398x; 1.0398x over previous
//
#include <hip/hip_runtime.h>

// Problem constants
#define Bsz 16
#define Dch 1024
#define Tsz 1024
#define Hsz 1024
#define Mtot (Bsz*Tsz)   // 16384
#define K2   (2*Dch)     // 2048
#define Ntot (3*Hsz)     // 3072
#define NCH  32          // scan chunks per chain
#define CL   32          // chunk length (NCH*CL == Tsz)
#define NT   32          // K-tiles in GEMM (K2/64)

typedef __attribute__((ext_vector_type(8))) short bf16x8;
typedef __attribute__((ext_vector_type(4))) float f32x4;

__device__ __forceinline__ unsigned short f2bf(float x) {
    unsigned u = __float_as_uint(x);
    u += 0x7FFFu + ((u >> 16) & 1u);   // round-to-nearest-even
    return (unsigned short)(u >> 16);
}
__device__ __forceinline__ float bf2f(unsigned short s) {
    return __uint_as_float(((unsigned)s) << 16);
}

// async global->LDS, 16B per lane, dest = ldsbase + lane*16 (wave-uniform base)
#define GLOAD_LDS16(gp, lp) \
    __builtin_amdgcn_global_load_lds((const __attribute__((address_space(1))) void*)(gp), \
                                     (__attribute__((address_space(3))) void*)(lp), 16, 0, 0)

// generic LDS pointer -> 32-bit LDS byte offset (for inline-asm ds_read)
#define LDSB(p) ((unsigned)(unsigned long long)(__attribute__((address_space(3))) const void*)(p))

// inline-asm ds_read_b128 (invisible to SIInsertWaitcnts; arrival enforced by
// our counted lgkmcnt + sched_barrier per rule #18)
#define DSR(dst, addr, off) \
    asm volatile("ds_read_b128 %0, %1 offset:" #off : "=v"(dst) : "v"(addr))

// counted lgkmcnt wait + scheduling fence
#define WAITLG(n) do { \
    asm volatile("s_waitcnt lgkmcnt(" #n ")" ::: "memory"); \
    __builtin_amdgcn_sched_barrier(0); } while (0)

// counted vmcnt wait + scheduling fence
#define VMC(n) do { \
    asm volatile("s_waitcnt vmcnt(" #n ")" ::: "memory"); \
    __builtin_amdgcn_sched_barrier(0); } while (0)

#define BAR __builtin_amdgcn_s_barrier()

// Merged prep: blocks [0,4096) build A2 (LDS transpose + causal shift + bf16 pack);
// blocks [4096,5632) cast conv_w fp32->bf16 (flat layout IS B^T row-major already).
__global__ __launch_bounds__(256)
void prep(const float* __restrict__ x, unsigned short* __restrict__ a2,
          const float* __restrict__ w, unsigned short* __restrict__ wb) {
    __shared__ float Xs[64][66];
    int bid = blockIdx.x;
    int tid = threadIdx.x;
    if (bid >= 4096) {
        int i0 = (bid - 4096) * 256 + tid;
        #pragma unroll
        for (int k = 0; k < 4; k++) {
            int i = i0 + k * (1536 * 256);
            float4 v = ((const float4*)w)[i];
            ushort4 r;
            r.x = f2bf(v.x); r.y = f2bf(v.y); r.z = f2bf(v.z); r.w = f2bf(v.w);
            ((ushort4*)wb)[i] = r;
        }
        return;
    }
    int b   = bid >> 8;
    int tt0 = ((bid >> 4) & 15) << 6;
    int dd0 = (bid & 15) << 6;
    int colt = tid & 63, rowq = tid >> 6;
    const size_t xbase = (size_t)b * (Dch * Tsz);
    #pragma unroll
    for (int r = 0; r < 16; r++) {
        int dd = r * 4 + rowq;
        Xs[dd][1 + colt] = x[xbase + (size_t)(dd0 + dd) * Tsz + tt0 + colt];
    }
    if (tid < 64) {
        Xs[tid][0] = (tt0 == 0) ? 0.f : x[xbase + (size_t)(dd0 + tid) * Tsz + tt0 - 1];
    }
    __syncthreads();
    #pragma unroll
    for (int r = 0; r < 16; r++) {
        int tr = r * 4 + rowq;
        int dc = colt;
        float v0 = Xs[dc][tr];       // x[t-1]
        float v1 = Xs[dc][tr + 1];   // x[t]
        unsigned pack = (unsigned)f2bf(v0) | ((unsigned)f2bf(v1) << 16);
        int m = (b << 10) + tt0 + tr;
        ((unsigned*)a2)[(size_t)m * (K2 / 2) + dd0 + dc] = pack;
    }
}

// ===========================================================================
// 256x256-tile, BK=64, 8-wave (2Mx4N), A-pair-clustered, split-publish pipeline.
//
// R4 change: MFMA clusters by A-PAIR (cluster p = af{2p,2p+1} x all 8 B-frags,
// 16 MFMA), and B(t+1) is PUBLISHED EARLY (vmcnt(2) at close(ph0) proves
// B0/B1(t+1), staged back at t-1.ph2/ph3), so B(t+1) reads issue at ph1/ph2
// into a parity-alternating bfr set (bfrE/bfrO). Per-wave read bursts become
// {4,8,8,4} per phase (was {4,8,0,12}) -> every burst fits its MFMA shadow;
// the tile-boundary burst shrinks 12->4 (af01(t+1) only).
// A-frags live in two ping-pong pair-slots afA/afB (16 VGPR each):
//   pre-ph0: afA=af01(t) | ph0: rd af23->afB, use afA | ph1: rd af45->afA +
//   rd bfrN[j01], use afB | ph2: rd af67->afB + rd bfrN[j23], use afA |
//   ph3: rd af01(t+1)->afA, use afB.
// Stage slots (1/phase): ph0 A1(t+1), ph1 A0(t+1), ph2 B1(t+2), ph3 B0(t+2).
// Ledger: at close(ph0) only A1(t+1)'s 2 loads outstanding -> vmcnt(2) proves
// B(t+1); at close(ph2) only B1(t+2)'s 2 outstanding -> vmcnt(2) proves
// A(t+1) (the general publish). Tail: t=30 drains vmcnt(0) at close(ph2).
// WAR: every staged region's last reader proved via a WAITLG that precedes a
// barrier that precedes the stage issue (audited per-region).
// ===========================================================================
#define MF(slot, bset, p) do { \
    _Pragma("unroll") for (int ks_ = 0; ks_ < 2; ++ks_) { \
      _Pragma("unroll") for (int d_ = 0; d_ < 2; ++d_) { \
        _Pragma("unroll") for (int j_ = 0; j_ < 4; ++j_) { \
          acc[2*(p)+d_][j_] = __builtin_amdgcn_mfma_f32_16x16x32_bf16( \
              slot[d_][ks_], bset[ks_][j_], acc[2*(p)+d_][j_], 0, 0, 0); \
        } } } } while (0)

__global__ __launch_bounds__(512, 2)
void gemm_gates(const unsigned short* __restrict__ A, const unsigned short* __restrict__ Bt,
                const float* __restrict__ bias,
                float* __restrict__ zc, float* __restrict__ fh, unsigned short* __restrict__ ob) {
    __shared__ __align__(16) unsigned short As[2][16384];
    __shared__ __align__(16) unsigned short Bs[2][16384];

    int tid  = threadIdx.x;
    int wv   = tid >> 6, lane = tid & 63;
    int wm   = wv >> 2, wn = wv & 3;        // 2 x 4 waves -> 128x64 per wave
    int lm   = lane & 15, q = lane >> 4;

    // XCD-aware bijective swizzle: 768 wgs = 8 XCDs x 96
    int bid = blockIdx.x;
    int swz = (bid & 7) * 96 + (bid >> 3);
    int mt = swz / 12, nt = swz % 12;       // 64 m-tiles x 12 n-tiles
    int m0 = mt << 8, n0 = nt << 8;

    const unsigned short* Abase = A  + (size_t)m0 * K2;
    const unsigned short* Bbase = Bt + (size_t)n0 * K2;

    // staging: lane covers row (wv*8 + l>>3), chunk (l&7); global chunk
    // pre-swizzled by ^(row&7) = ^(l>>3); LDS dest linear.
    int loff   = (wv * 8 + (lane >> 3)) * K2 + (((lane & 7) ^ (lane >> 3)) << 3);
    int ldsoff = wv * 8 * 64;

    // fragment-read constants (ushort units)
    int sw  = lm & 7;
    int kc0 = (q ^ sw) << 3;          // k-slice 0 -> chunks 0..3
    int kc1 = ((4 + q) ^ sw) << 3;    // k-slice 1 -> chunks 4..7
    int aoff = (wm * 128 + lm) * 64;
    int boff = (wn * 64 + lm) * 64;

    unsigned asb = LDSB(&As[0][0]);
    unsigned bsb = LDSB(&Bs[0][0]);
    unsigned aA0 = asb + (unsigned)(aoff + kc0) * 2u;
    unsigned aA1 = asb + (unsigned)(aoff + kc1) * 2u;
    unsigned aB0 = bsb + (unsigned)(boff + kc0) * 2u;
    unsigned aB1 = bsb + (unsigned)(boff + kc1) * 2u;

    f32x4 acc[8][4] = {};
    bf16x8 afA[2][2], afB[2][2];      // ping-pong A-pair slots [d][kslice]
    bf16x8 bfrE[2][4], bfrO[2][4];    // per-tile-parity B sets [kslice][j]

#define STAGE_A(t, h) do { \
    const unsigned short* g_ = Abase + (h) * (128 * K2) + (t) * 64 + loff; \
    unsigned short* l_ = &As[(t) & 1][(h) * 8192 + ldsoff]; \
    GLOAD_LDS16(g_, l_); \
    GLOAD_LDS16(g_ + 64 * K2, l_ + 64 * 64); } while (0)
#define STAGE_B(t, h) do { \
    const unsigned short* g_ = Bbase + (h) * (128 * K2) + (t) * 64 + loff; \
    unsigned short* l_ = &Bs[(t) & 1][(h) * 8192 + ldsoff]; \
    GLOAD_LDS16(g_, l_); \
    GLOAD_LDS16(g_ + 64 * K2, l_ + 64 * 64); } while (0)

// A-pair read: pair at byte offsets o0/o1 (rows 2p, 2p+1), both k-slices
#define R_AFP(slot, o0, o1, bo) do { \
    DSR(slot[0][0], aA0 + (bo), o0); DSR(slot[0][1], aA1 + (bo), o0); \
    DSR(slot[1][0], aA0 + (bo), o1); DSR(slot[1][1], aA1 + (bo), o1); } while (0)
// B half-reads (j=0,1 / j=2,3), both k-slices
#define R_BH0(set, bo) do { \
    DSR(set[0][0], aB0 + (bo), 0);    DSR(set[1][0], aB1 + (bo), 0); \
    DSR(set[0][1], aB0 + (bo), 2048); DSR(set[1][1], aB1 + (bo), 2048); } while (0)
#define R_BH1(set, bo) do { \
    DSR(set[0][2], aB0 + (bo), 4096); DSR(set[1][2], aB1 + (bo), 4096); \
    DSR(set[0][3], aB0 + (bo), 6144); DSR(set[1][3], aB1 + (bo), 6144); } while (0)

#define PRIO1 __builtin_amdgcn_s_setprio(1)
#define PRIO0 do { __builtin_amdgcn_s_setprio(0); __builtin_amdgcn_sched_barrier(0); } while (0)

// Phase macros (steady-state). T is the current tile index (runtime).
#define PH0(T, CB, BC) do { \
    R_AFP(afB, 4096, 6144, CB); \
    STAGE_A((T) + 1, 1); \
    WAITLG(4); \
    PRIO1; MF(afA, BC, 0); PRIO0; } while (0)
#define PH1(T, CB, NB, BC, BN) do { \
    R_AFP(afA, 8192, 10240, CB); \
    R_BH0(BN, NB); \
    STAGE_A((T) + 1, 0); \
    WAITLG(8); \
    PRIO1; MF(afB, BC, 1); PRIO0; } while (0)
#define PH2(T, CB, NB, BC, BN) do { \
    R_AFP(afB, 12288, 14336, CB); \
    R_BH1(BN, NB); \
    STAGE_B((T) + 2, 1); \
    WAITLG(8); \
    PRIO1; MF(afA, BC, 2); PRIO0; } while (0)
#define PH3(T, NB, BC) do { \
    R_AFP(afA, 0, 2048, NB); \
    STAGE_B((T) + 2, 0); \
    WAITLG(4); \
    PRIO1; MF(afB, BC, 3); PRIO0; } while (0)

    // ---- Prologue: tile0 fully + B(1); read af01(0) + all bfrE(0).
    STAGE_A(0, 0); STAGE_A(0, 1); STAGE_B(0, 0); STAGE_B(0, 1);
    STAGE_B(1, 1); STAGE_B(1, 0);
    VMC(4); BAR;                       // tile0's 8 loads landed
    R_AFP(afA, 0, 2048, 0u);
    R_BH0(bfrE, 0u); R_BH1(bfrE, 0u);
    __builtin_amdgcn_sched_barrier(0);

    #pragma unroll 1
    for (int tp = 0; tp < 15; ++tp) {
        int t0 = 2 * tp;
        // even tile: cur=buf0, nxt=buf1, consume bfrE, fill bfrO
        PH0(t0, 0u, bfrE);                 VMC(2); BAR;   // proves B(t0+1)
        PH1(t0, 0u, 32768u, bfrE, bfrO);           BAR;
        PH2(t0, 0u, 32768u, bfrE, bfrO);   VMC(2); BAR;   // publish A(t0+1)
        PH3(t0, 32768u, bfrE);                     BAR;
        // odd tile
        PH0(t0 + 1, 32768u, bfrO);         VMC(2); BAR;
        PH1(t0 + 1, 32768u, 0u, bfrO, bfrE);       BAR;
        PH2(t0 + 1, 32768u, 0u, bfrO, bfrE); VMC(2); BAR;
        PH3(t0 + 1, 0u, bfrO);                     BAR;
    }

    // ---- peeled t=30 (even; stages of t+2=32 dropped; drain at close ph2)
    PH0(30, 0u, bfrE);                     VMC(2); BAR;
    PH1(30, 0u, 32768u, bfrE, bfrO);               BAR;
    R_AFP(afB, 12288, 14336, 0u);
    R_BH1(bfrO, 32768u);
    WAITLG(8);
    PRIO1; MF(afA, bfrE, 2); PRIO0;
    VMC(0); BAR;                                   // drain: A(31) landed
    R_AFP(afA, 0, 2048, 32768u);                   // af01(31)
    WAITLG(4);
    PRIO1; MF(afB, bfrE, 3); PRIO0;
    BAR;

    // ---- peeled t=31 (cur=buf1, consume bfrO; no stages, no vmcnt)
    R_AFP(afB, 4096, 6144, 32768u);
    WAITLG(4);
    PRIO1; MF(afA, bfrO, 0); PRIO0; BAR;
    R_AFP(afA, 8192, 10240, 32768u);
    WAITLG(4);
    PRIO1; MF(afB, bfrO, 1); PRIO0; BAR;
    R_AFP(afB, 12288, 14336, 32768u);
    WAITLG(4);
    PRIO1; MF(afA, bfrO, 2); PRIO0; BAR;
    WAITLG(0);
    PRIO1; MF(afB, bfrO, 3); PRIO0;

    // Epilogue: C/D layout col=lane&15, row=(lane>>4)*4+reg.
    int gt = nt >> 2;   // 0:z(tanh) 1:f(sigm) 2:o(sigm->bf16)
    #pragma unroll
    for (int i = 0; i < 8; ++i) {
        int mrow = m0 + wm * 128 + i * 16 + q * 4;
        #pragma unroll
        for (int j = 0; j < 4; ++j) {
            int n = n0 + wn * 64 + j * 16 + lm;
            float bv = bias[n];
            int hcol = n & 1023;
            #pragma unroll
            for (int r = 0; r < 4; ++r) {
                float g = acc[i][j][r] + bv;
                size_t idx = (size_t)(mrow + r) * Hsz + hcol;
                if (gt == 0) {
                    float e = __expf(2.f * g);
                    zc[idx] = __fdividef(e - 1.f, e + 1.f);
                } else {
                    float s = __fdividef(1.f, 1.f + __expf(-g));
                    if (gt == 1) fh[idx] = s;
                    else         ob[idx] = f2bf(s);
                }
            }
        }
    }
}

// ---- chunked fo-pooling scan: c_t = z + f*(c - z), c_0 = 0 ----
// NCH=32 chunks of CL=32 -> 1024 blocks (2x parallelism vs NCH=16).
__global__ __launch_bounds__(256)
void scan1(const float* __restrict__ zc, const float* __restrict__ fh,
           float* __restrict__ Aw, float* __restrict__ Bw) {
    int blk = blockIdx.x;                 // 16 b * 32 ch * 2 hb = 1024
    int hb = blk & 1, ch = (blk >> 1) & 31, b = blk >> 6;
    int h = hb * 512 + threadIdx.x * 2;
    size_t base = ((size_t)b << 20) + ((size_t)(ch * CL) << 10) + h;
    float ax = 1.f, ay = 1.f, bx = 0.f, by = 0.f;
    #pragma unroll 8
    for (int s = 0; s < CL; s++) {
        size_t idx = base + ((size_t)s << 10);
        float2 z = *(const float2*)&zc[idx];
        float2 f = *(const float2*)&fh[idx];
        ax *= f.x; ay *= f.y;
        bx = z.x + f.x * (bx - z.x);
        by = z.y + f.y * (by - z.y);
    }
    int o = (ch * Bsz + b) * Hsz + h;
    *(float2*)&Aw[o] = make_float2(ax, ay);
    *(float2*)&Bw[o] = make_float2(bx, by);
}

__global__ __launch_bounds__(256)
void scan3(float* __restrict__ zc, float* __restrict__ fh,
           const unsigned short* __restrict__ ob,
           const float* __restrict__ Aw, const float* __restrict__ Bw) {
    int blk = blockIdx.x;                 // 1024
    int hb = blk & 1, ch = (blk >> 1) & 31, b = blk >> 6;
    int h = hb * 512 + threadIdx.x * 2;
    float cx = 0.f, cy = 0.f;
    for (int cp = 0; cp < ch; cp++) {     // chunk-entry state (block-uniform trip)
        int o = (cp * Bsz + b) * Hsz + h;
        float2 A = *(const float2*)&Aw[o];
        float2 B = *(const float2*)&Bw[o];
        cx = A.x * cx + B.x;
        cy = A.y * cy + B.y;
    }
    size_t base = ((size_t)b << 20) + ((size_t)(ch * CL) << 10) + h;
    #pragma unroll 8
    for (int s = 0; s < CL; s++) {
        size_t idx = base + ((size_t)s << 10);
        float2 z = *(const float2*)&zc[idx];
        float2 f = *(const float2*)&fh[idx];
        unsigned ov = *(const unsigned*)&ob[idx];   // two bf16 o-gates
        cx = z.x + f.x * (cx - z.x);
        cy = z.y + f.y * (cy - z.y);
        *(float2*)&zc[idx] = make_float2(cx, cy);
        float ox = bf2f((unsigned short)(ov & 0xFFFF));
        float oy = bf2f((unsigned short)(ov >> 16));
        *(float2*)&fh[idx] = make_float2(ox * cx, oy * cy);
    }
}

extern "C" void kernel_launch(void* const* d_in, const int* in_sizes, int n_in,
                              void* d_out, int out_size, void* d_ws, size_t ws_size,
                              hipStream_t stream) {
    const float* x    = (const float*)d_in[0];   // [16,1024,1024]
    const float* w    = (const float*)d_in[1];   // [3072,1024,2]
    const float* bias = (const float*)d_in[2];   // [3072]
    float* zc = (float*)d_out;                               // c_seq out (holds z pre-scan)
    float* fh = (float*)d_out + (size_t)Mtot * Hsz;          // h_seq out (holds f pre-scan)
    unsigned short* a2 = (unsigned short*)d_ws;              // 64 MB
    unsigned short* wb = a2 + (size_t)Mtot * K2;             // 12.6 MB
    unsigned short* ob = wb + (size_t)Ntot * K2;             // 32 MB (o gate, bf16)
    float* Aw = (float*)(ob + (size_t)Mtot * Hsz);           // 2 MB
    float* Bw = Aw + NCH * Bsz * Hsz;                        // 2 MB

    hipLaunchKernelGGL(prep, dim3(5632), dim3(256), 0, stream, x, a2, w, wb);
    hipLaunchKernelGGL(gemm_gates, dim3(768), dim3(512), 0, stream, a2, wb, bias, zc, fh, ob);
    hipLaunchKernelGGL(scan1, dim3(1024), dim3(256), 0, stream, zc, fh, Aw, Bw);
    hipLaunchKernelGGL(scan3, dim3(1024), dim3(256), 0, stream, zc, fh, ob, Aw, Bw);
}